// Round 2
// baseline (726.560 us; speedup 1.0000x reference)
//
#include <hip/hip_runtime.h>

#define D_FEAT 64
#define M_LEN 32
#define BLOCK 512
#define MAXSEG 512
#define HALF_J 16
#define CHUNK 8
#define BIGF 1e30f

// One block per segment. Thread t owns column t of the segment.
// Phase 1: c[j] = sum_d q[d][j] * X[d][base+col], xx = sum_d x^2.
//   X loads: coalesced, nontemporal, TRIPLE-BUFFERED software pipeline:
//   chunk k is consumed while chunks k+1,k+2 (16 loads) are in flight.
//   Issue->consume distance ~2x528 cyc > ~900 cyc HBM latency, so each wave
//   hides its own load latency (R1 showed occupancy does NOT fix this:
//   waves convoy -- all stall together on the rolled-loop load gap).
//   Full unroll => compile-time row indices => SGPR row bases, and the
//   compiler can hoist/pipeline the q s_loads across rows.
// Phase 2: h[j][t] = xx - 2*c[j] staged in LDS in TWO j-halves of 16 rows
//   (32 KB). dist[p] = sum_j h[j][p+j] (QQ dropped: additive const cancels
//   in min-max scaling), block-min -> mins[seg].
__global__ __launch_bounds__(BLOCK, 4) void seg_min_kernel(
    const float* __restrict__ X, const float* __restrict__ q,
    const int* __restrict__ cumlens, float* __restrict__ mins, long long T)
{
    __shared__ float h[HALF_J * MAXSEG];   // 32 KB

    const int seg  = blockIdx.x;
    const int base = cumlens[seg];
    const int len  = cumlens[seg + 1] - base;   // == 512 here; <= MAXSEG assumed
    const int tid  = threadIdx.x;
    // clamp instead of branch: keeps control flow uniform so q-loads scalarize;
    // clamped threads redundantly recompute column len-1 (benign same-value race)
    const int col  = tid < len ? tid : (len > 0 ? len - 1 : 0);

    float c[M_LEN];
    #pragma unroll
    for (int j = 0; j < M_LEN; ++j) c[j] = 0.0f;
    float xx = 0.0f;

    const float* xp = X + (size_t)base + (size_t)col;

    // triple buffer: rows 8k..8k+7 live in vb3[k%3]; all indices compile-time
    float vb3[3][CHUNK];
    #pragma unroll
    for (int b = 0; b < 3; ++b)
        #pragma unroll
        for (int dd = 0; dd < CHUNK; ++dd)
            vb3[b][dd] = __builtin_nontemporal_load(
                xp + (size_t)(b * CHUNK + dd) * (size_t)T);

    #pragma unroll
    for (int k = 0; k < D_FEAT / CHUNK; ++k) {
        // consume chunk k (rows 8k..8k+7)
        #pragma unroll
        for (int dd = 0; dd < CHUNK; ++dd) {
            const float x = vb3[k % 3][dd];
            xx = fmaf(x, x, xx);
            const float* __restrict__ qd = q + (k * CHUNK + dd) * M_LEN;  // uniform -> s_load
            #pragma unroll
            for (int j = 0; j < M_LEN; ++j)
                c[j] = fmaf(x, qd[j], c[j]);
        }
        // refill the just-freed buffer with chunk k+3
        if (k + 3 < D_FEAT / CHUNK) {
            #pragma unroll
            for (int dd = 0; dd < CHUNK; ++dd)
                vb3[k % 3][dd] = __builtin_nontemporal_load(
                    xp + (size_t)((k + 3) * CHUNK + dd) * (size_t)T);
        }
    }

    // ---- half A: j = 0..15 ----
    // h[j][t] = xx - 2*c[j]; per fixed j lanes are consecutive -> conflict-free
    #pragma unroll
    for (int j = 0; j < HALF_J; ++j)
        h[j * MAXSEG + col] = fmaf(-2.0f, c[j], xx);
    __syncthreads();

    const bool valid = (tid + M_LEN - 1 < len);   // valid window start: tid <= len - M
    float acc = 0.0f;
    if (valid) {
        #pragma unroll
        for (int j = 0; j < HALF_J; ++j)
            acc += h[j * MAXSEG + tid + j];   // fixed j: consecutive lanes -> conflict-free
    }
    __syncthreads();   // all reads of half A done before overwrite

    // ---- half B: j = 16..31 ----
    #pragma unroll
    for (int j = HALF_J; j < M_LEN; ++j)
        h[(j - HALF_J) * MAXSEG + col] = fmaf(-2.0f, c[j], xx);
    __syncthreads();

    float dist = BIGF;
    if (valid) {
        #pragma unroll
        for (int j = HALF_J; j < M_LEN; ++j)
            acc += h[(j - HALF_J) * MAXSEG + tid + j];
        dist = acc;
    }

    // wave (64-lane) min reduction
    #pragma unroll
    for (int off = 32; off > 0; off >>= 1)
        dist = fminf(dist, __shfl_down(dist, off));

    __syncthreads();                 // all h reads done; safe to reuse h as scratch
    if ((tid & 63) == 0) h[tid >> 6] = dist;
    __syncthreads();
    if (tid == 0) {
        float m = h[0];
        #pragma unroll
        for (int w = 1; w < BLOCK / 64; ++w) m = fminf(m, h[w]);
        mins[seg] = m;
    }
}

// Single block: lo/hi over mins, then out[i,k] = scaled[i]*w[k] + b[k]
__global__ __launch_bounds__(1024) void finalize_kernel(
    const float* __restrict__ mins, const float* __restrict__ lw,
    const float* __restrict__ lb, float* __restrict__ out, int nseg)
{
    __shared__ float slo[16], shi[16];
    const int tid = threadIdx.x;
    float lo = BIGF, hi = -BIGF;
    for (int i = tid; i < nseg; i += blockDim.x) {
        float v = mins[i];
        lo = fminf(lo, v);
        hi = fmaxf(hi, v);
    }
    #pragma unroll
    for (int off = 32; off > 0; off >>= 1) {
        lo = fminf(lo, __shfl_down(lo, off));
        hi = fmaxf(hi, __shfl_down(hi, off));
    }
    const int nw = blockDim.x >> 6;
    if ((tid & 63) == 0) { slo[tid >> 6] = lo; shi[tid >> 6] = hi; }
    __syncthreads();
    if (tid == 0) {
        float l = slo[0], h2 = shi[0];
        for (int w = 1; w < nw; ++w) { l = fminf(l, slo[w]); h2 = fmaxf(h2, shi[w]); }
        slo[0] = l; shi[0] = h2;
    }
    __syncthreads();
    lo = slo[0]; hi = shi[0];
    const float inv = 1.0f / (hi - lo + 1e-16f);
    const float w0 = lw[0], w1 = lw[1], b0 = lb[0], b1 = lb[1];
    for (int i = tid; i < nseg; i += blockDim.x) {
        float s = (mins[i] - lo) * inv;
        out[2 * i]     = fmaf(s, w0, b0);
        out[2 * i + 1] = fmaf(s, w1, b1);
    }
}

extern "C" void kernel_launch(void* const* d_in, const int* in_sizes, int n_in,
                              void* d_out, int out_size, void* d_ws, size_t ws_size,
                              hipStream_t stream) {
    const float* X   = (const float*)d_in[0];
    const float* q   = (const float*)d_in[1];
    const float* lw  = (const float*)d_in[2];
    const float* lb  = (const float*)d_in[3];
    const int*   cum = (const int*)d_in[4];

    const int n_seg = in_sizes[4] - 1;
    const long long T = (long long)in_sizes[0] / D_FEAT;

    float* mins = (float*)d_ws;          // n_seg floats, fully written each call
    float* out  = (float*)d_out;

    seg_min_kernel<<<n_seg, BLOCK, 0, stream>>>(X, q, cum, mins, T);
    finalize_kernel<<<1, 1024, 0, stream>>>(mins, lw, lb, out, n_seg);
}

// Round 3
// 691.754 us; speedup vs baseline: 1.0503x; 1.0503x over previous
//
#include <hip/hip_runtime.h>

#define D_FEAT 64
#define M_LEN 32
#define BLOCK 256            // 2 cols/thread -> covers 512-col segment
#define MAXSEG 512
#define HALF_J 16
#define CHUNK 8
#define BIGF 1e30f

// One block per segment. Thread t owns columns 2t and 2t+1 (float2 loads:
// 8 B/lane instead of 4 B/lane -> half the VMEM instructions, coalescing
// sweet spot; NT hint dropped -- R0-R2 showed occupancy and SW-pipelining
// are NOT the bottleneck, so this round isolates the memory-path itself).
// Each q s_load dword now feeds 2 FMAs (c0 and c1), halving scalar-stream
// pressure per FLOP.
// Phase 1: c{0,1}[j] = sum_d q[d][j]*X[d][base+col{0,1}], xx{0,1} = sum x^2.
//   Per-column accumulation order identical to previous kernel (d ascending,
//   j ascending) -> bit-identical results.
// Phase 2: h[j][t] = xx - 2*c[j] staged in LDS in TWO j-halves of 16 rows
//   (32 KB). dist[p] = sum_j h[j][p+j] (QQ dropped: additive const cancels
//   in min-max scaling), block-min -> mins[seg].
// Assumes segment bases are even and len>=2 (true here: base = 512*seg) so
// float2 loads are 8 B aligned.
__global__ __launch_bounds__(BLOCK, 4) void seg_min_kernel(
    const float* __restrict__ X, const float* __restrict__ q,
    const int* __restrict__ cumlens, float* __restrict__ mins, long long T)
{
    __shared__ float h[HALF_J * MAXSEG];   // 32 KB

    const int seg  = blockIdx.x;
    const int base = cumlens[seg];
    const int len  = cumlens[seg + 1] - base;   // == 512 here; <= MAXSEG assumed
    const int tid  = threadIdx.x;

    // pair-start column; clamp (not branch) keeps control flow uniform so the
    // q loads scalarize. Clamped threads redundantly recompute the last pair
    // (benign same-value LDS race; their windows are gated invalid below).
    int p0 = 2 * tid;
    if (p0 > len - 2) p0 = (len >= 2) ? (len - 2) : 0;

    float c0[M_LEN], c1[M_LEN];
    #pragma unroll
    for (int j = 0; j < M_LEN; ++j) { c0[j] = 0.0f; c1[j] = 0.0f; }
    float xx0 = 0.0f, xx1 = 0.0f;

    const float* xp = X + (size_t)base + (size_t)p0;

    #pragma unroll 1   // keep rolled: bounds VGPR pressure and I-cache (R2 lesson)
    for (int d0 = 0; d0 < D_FEAT; d0 += CHUNK) {
        float2 xv[CHUNK];
        #pragma unroll
        for (int dd = 0; dd < CHUNK; ++dd)
            xv[dd] = *reinterpret_cast<const float2*>(
                xp + (size_t)(d0 + dd) * (size_t)T);

        #pragma unroll
        for (int dd = 0; dd < CHUNK; ++dd) {
            const float x0 = xv[dd].x, x1 = xv[dd].y;
            xx0 = fmaf(x0, x0, xx0);
            xx1 = fmaf(x1, x1, xx1);
            const float* __restrict__ qd = q + (d0 + dd) * M_LEN;  // uniform -> s_load
            #pragma unroll
            for (int j = 0; j < M_LEN; ++j) {
                const float qv = qd[j];
                c0[j] = fmaf(x0, qv, c0[j]);
                c1[j] = fmaf(x1, qv, c1[j]);
            }
        }
    }

    // ---- half A: j = 0..15 ----
    // per fixed j lanes write stride-2 floats -> 2-way bank alias (free, m136)
    #pragma unroll
    for (int j = 0; j < HALF_J; ++j) {
        h[j * MAXSEG + p0]     = fmaf(-2.0f, c0[j], xx0);
        h[j * MAXSEG + p0 + 1] = fmaf(-2.0f, c1[j], xx1);
    }
    __syncthreads();

    const bool v0 = (p0 + M_LEN - 1 < len);   // window start p0   valid
    const bool v1 = (p0 + M_LEN     < len);   // window start p0+1 valid
    float a0 = 0.0f, a1 = 0.0f;
    if (v0) {
        #pragma unroll
        for (int j = 0; j < HALF_J; ++j) a0 += h[j * MAXSEG + p0 + j];
    }
    if (v1) {
        #pragma unroll
        for (int j = 0; j < HALF_J; ++j) a1 += h[j * MAXSEG + p0 + 1 + j];
    }
    __syncthreads();   // all reads of half A done before overwrite

    // ---- half B: j = 16..31 ----
    #pragma unroll
    for (int j = HALF_J; j < M_LEN; ++j) {
        h[(j - HALF_J) * MAXSEG + p0]     = fmaf(-2.0f, c0[j], xx0);
        h[(j - HALF_J) * MAXSEG + p0 + 1] = fmaf(-2.0f, c1[j], xx1);
    }
    __syncthreads();

    float dist = BIGF;
    if (v0) {
        #pragma unroll
        for (int j = HALF_J; j < M_LEN; ++j) a0 += h[(j - HALF_J) * MAXSEG + p0 + j];
        dist = a0;
    }
    if (v1) {
        #pragma unroll
        for (int j = HALF_J; j < M_LEN; ++j) a1 += h[(j - HALF_J) * MAXSEG + p0 + 1 + j];
        dist = fminf(dist, a1);
    }

    // wave (64-lane) min reduction
    #pragma unroll
    for (int off = 32; off > 0; off >>= 1)
        dist = fminf(dist, __shfl_down(dist, off));

    __syncthreads();                 // all h reads done; safe to reuse h as scratch
    if ((tid & 63) == 0) h[tid >> 6] = dist;
    __syncthreads();
    if (tid == 0) {
        float m = h[0];
        #pragma unroll
        for (int w = 1; w < BLOCK / 64; ++w) m = fminf(m, h[w]);
        mins[seg] = m;
    }
}

// Single block: lo/hi over mins, then out[i,k] = scaled[i]*w[k] + b[k]
__global__ __launch_bounds__(1024) void finalize_kernel(
    const float* __restrict__ mins, const float* __restrict__ lw,
    const float* __restrict__ lb, float* __restrict__ out, int nseg)
{
    __shared__ float slo[16], shi[16];
    const int tid = threadIdx.x;
    float lo = BIGF, hi = -BIGF;
    for (int i = tid; i < nseg; i += blockDim.x) {
        float v = mins[i];
        lo = fminf(lo, v);
        hi = fmaxf(hi, v);
    }
    #pragma unroll
    for (int off = 32; off > 0; off >>= 1) {
        lo = fminf(lo, __shfl_down(lo, off));
        hi = fmaxf(hi, __shfl_down(hi, off));
    }
    const int nw = blockDim.x >> 6;
    if ((tid & 63) == 0) { slo[tid >> 6] = lo; shi[tid >> 6] = hi; }
    __syncthreads();
    if (tid == 0) {
        float l = slo[0], h2 = shi[0];
        for (int w = 1; w < nw; ++w) { l = fminf(l, slo[w]); h2 = fmaxf(h2, shi[w]); }
        slo[0] = l; shi[0] = h2;
    }
    __syncthreads();
    lo = slo[0]; hi = shi[0];
    const float inv = 1.0f / (hi - lo + 1e-16f);
    const float w0 = lw[0], w1 = lw[1], b0 = lb[0], b1 = lb[1];
    for (int i = tid; i < nseg; i += blockDim.x) {
        float s = (mins[i] - lo) * inv;
        out[2 * i]     = fmaf(s, w0, b0);
        out[2 * i + 1] = fmaf(s, w1, b1);
    }
}

extern "C" void kernel_launch(void* const* d_in, const int* in_sizes, int n_in,
                              void* d_out, int out_size, void* d_ws, size_t ws_size,
                              hipStream_t stream) {
    const float* X   = (const float*)d_in[0];
    const float* q   = (const float*)d_in[1];
    const float* lw  = (const float*)d_in[2];
    const float* lb  = (const float*)d_in[3];
    const int*   cum = (const int*)d_in[4];

    const int n_seg = in_sizes[4] - 1;
    const long long T = (long long)in_sizes[0] / D_FEAT;

    float* mins = (float*)d_ws;          // n_seg floats, fully written each call
    float* out  = (float*)d_out;

    seg_min_kernel<<<n_seg, BLOCK, 0, stream>>>(X, q, cum, mins, T);
    finalize_kernel<<<1, 1024, 0, stream>>>(mins, lw, lb, out, n_seg);
}